// Round 1
// baseline (160.969 us; speedup 1.0000x reference)
//
#include <hip/hip_runtime.h>

// PPO loss, T = 2^23 fp32 elements.
// out = -sum(min(ratio*adv, clip(ratio)*adv)) + C1*sum((v - ret)^2) - C2*sum(p*log(p+1e-5))
// adv = reverse scan: gae = (g*l)*gae + (r_t - v_t + g*v_{t+1});  ret = reverse scan: acc = g*acc + r_t.
// Constant-coefficient scans => per-chunk exact-to-fp32 via geometric halo (W=2048).

#define T_TOTAL  8388608
#define L_CHUNK  8192
#define NBLK     (T_TOTAL / L_CHUNK)   // 1024
#define NT       512
#define M        16                    // elems per thread (NT*M == L_CHUNK)
#define W_HALO   2048                  // halo window (4 elems/thread)

#define EPSF   0.2f
#define GAMMAF 0.99f
#define C1F    0.5f
#define C2F    0.01f

// constant-folded powers
#define AG1  (0.99f * 0.95f)                 // gamma*lambda
#define AG2  (AG1 * AG1)
#define AG4  (AG2 * AG2)
#define AG8  (AG4 * AG4)
#define AG16 (AG8 * AG8)
#define G2   (GAMMAF * GAMMAF)
#define G4   (G2 * G2)
#define G8   (G4 * G4)
#define G16  (G8 * G8)

__global__ __launch_bounds__(NT) void ppo_loss_kernel(
    const float* __restrict__ probs,
    const float* __restrict__ probs_old,
    const float* __restrict__ rewards,
    const float* __restrict__ values,
    float* __restrict__ out)
{
    __shared__ float sg[NT];
    __shared__ float sr[NT];

    const int j = threadIdx.x;
    const int c = blockIdx.x;
    const long base = (long)c * L_CHUNK;

    // ---------------- Phase A: halo carries (next W_HALO elements) ----------------
    // K_gae = sum_{i<W} (gl)^i * delta_{end+i},  K_ret = sum_{i<W} g^i * r_{end+i}
    float hp_g = 0.0f, hp_r = 0.0f;
    if (c != NBLK - 1) {
        const long hb = base + L_CHUNK + 4L * j;       // 16B aligned
        const float4 r4 = *reinterpret_cast<const float4*>(rewards + hb);
        const float4 v4 = *reinterpret_cast<const float4*>(values + hb);
        const float  vn = values[hb + 4];              // always in range (c < NBLK-1)
        const float d0 = r4.x - v4.x + GAMMAF * v4.y;
        const float d1 = r4.y - v4.y + GAMMAF * v4.z;
        const float d2 = r4.z - v4.z + GAMMAF * v4.w;
        const float d3 = r4.w - v4.w + GAMMAF * vn;
        hp_g = d0 + AG1 * (d1 + AG1 * (d2 + AG1 * d3));
        hp_r = r4.x + GAMMAF * (r4.y + GAMMAF * (r4.z + GAMMAF * r4.w));
    }
    sg[j] = hp_g; sr[j] = hp_r;
    __syncthreads();
    {
        float fg = AG4, fr = G4;    // pair distance = 4 elements at level 0
        for (int n = NT / 2; n >= 1; n >>= 1) {
            float tg = 0.0f, tr = 0.0f;
            if (j < n) {
                tg = sg[2 * j] + fg * sg[2 * j + 1];
                tr = sr[2 * j] + fr * sr[2 * j + 1];
            }
            __syncthreads();
            if (j < n) { sg[j] = tg; sr[j] = tr; }
            __syncthreads();
            fg *= fg; fr *= fr;
        }
    }
    const float Kg = sg[0];
    const float Kr = sr[0];
    __syncthreads();

    // ---------------- Phase B: main chunk, per-thread run of M elems ----------------
    const long g0 = base + (long)j * M;

    float r[M], v[M], d[M];
#pragma unroll
    for (int b = 0; b < M / 4; ++b) {
        const float4 rr = *reinterpret_cast<const float4*>(rewards + g0 + 4 * b);
        const float4 vv = *reinterpret_cast<const float4*>(values  + g0 + 4 * b);
        r[4 * b + 0] = rr.x; r[4 * b + 1] = rr.y; r[4 * b + 2] = rr.z; r[4 * b + 3] = rr.w;
        v[4 * b + 0] = vv.x; v[4 * b + 1] = vv.y; v[4 * b + 2] = vv.z; v[4 * b + 3] = vv.w;
    }
    const float v_next = (g0 + M < T_TOTAL) ? values[g0 + M] : 0.0f;
#pragma unroll
    for (int i = 0; i < M - 1; ++i) d[i] = r[i] - v[i] + GAMMAF * v[i + 1];
    d[M - 1] = r[M - 1] - v[M - 1] + GAMMAF * v_next;

    // thread-local Horner partials: P = sum_i a^i x_i over the run
    float Pg = 0.0f, Pr = 0.0f;
#pragma unroll
    for (int i = M - 1; i >= 0; --i) {
        Pg = AG1   * Pg + d[i];
        Pr = GAMMAF * Pr + r[i];
    }

    // inclusive suffix scan across threads, weight w = a^M; halo injected at j = NT-1
    sg[j] = (j == NT - 1) ? (Pg + AG16 * Kg) : Pg;
    sr[j] = (j == NT - 1) ? (Pr + G16  * Kr) : Pr;
    __syncthreads();
    {
        float fg = AG16, fr = G16;
        for (int s = 1; s < NT; s <<= 1) {
            const float tg = sg[j] + ((j + s < NT) ? fg * sg[j + s] : 0.0f);
            const float tr = sr[j] + ((j + s < NT) ? fr * sr[j + s] : 0.0f);
            __syncthreads();
            sg[j] = tg; sr[j] = tr;
            __syncthreads();
            fg *= fg; fr *= fr;
        }
    }
    const float cg = (j < NT - 1) ? sg[j + 1] : Kg;   // scan value entering my run from the right
    const float cr = (j < NT - 1) ? sr[j + 1] : Kr;
    __syncthreads();

    // ---------------- Phase C: in-register reverse scan fused with loss ----------------
    float y = cg, tt = cr;
    float acc = 0.0f;
#pragma unroll
    for (int b = M / 4 - 1; b >= 0; --b) {
        const float4 p4 = *reinterpret_cast<const float4*>(probs     + g0 + 4 * b);
        const float4 q4 = *reinterpret_cast<const float4*>(probs_old + g0 + 4 * b);
        const float pa[4] = { p4.x, p4.y, p4.z, p4.w };
        const float qa[4] = { q4.x, q4.y, q4.z, q4.w };
#pragma unroll
        for (int k = 3; k >= 0; --k) {
            const int i = 4 * b + k;
            y  = AG1    * y  + d[i];    // advantage at i
            tt = GAMMAF * tt + r[i];    // return target at i
            const float ratio = __fdividef(pa[k], qa[k]);
            const float cl    = fminf(fmaxf(ratio, 1.0f - EPSF), 1.0f + EPSF);
            const float term  = fminf(ratio * y, cl * y);
            const float vd    = v[i] - tt;
            acc += C1F * vd * vd - term - C2F * pa[k] * __logf(pa[k] + 1e-5f);
        }
    }

    // ---------------- Phase D: block reduce + atomic ----------------
    sg[j] = acc;
    __syncthreads();
    for (int n = NT / 2; n >= 64; n >>= 1) {
        if (j < n) sg[j] += sg[j + n];   // writers [0,n) / readers [n,2n) disjoint
        __syncthreads();
    }
    if (j < 64) {
        float x = sg[j];
        for (int off = 32; off >= 1; off >>= 1)
            x += __shfl_down(x, off, 64);
        if (j == 0) atomicAdd(out, x);
    }
}

extern "C" void kernel_launch(void* const* d_in, const int* in_sizes, int n_in,
                              void* d_out, int out_size, void* d_ws, size_t ws_size,
                              hipStream_t stream) {
    const float* probs     = (const float*)d_in[0];
    const float* probs_old = (const float*)d_in[1];
    const float* rewards   = (const float*)d_in[2];
    const float* values    = (const float*)d_in[3];
    float* out = (float*)d_out;

    hipMemsetAsync(out, 0, sizeof(float), stream);   // d_out is poisoned 0xAA before every call
    ppo_loss_kernel<<<NBLK, NT, 0, stream>>>(probs, probs_old, rewards, values, out);
}

// Round 2
// 154.003 us; speedup vs baseline: 1.0452x; 1.0452x over previous
//
#include <hip/hip_runtime.h>

// PPO loss, T = 2^23 fp32.
// out = -sum(min(ratio*adv, clip(ratio)*adv)) + C1*sum((v-ret)^2) - C2*sum(p*log(p+1e-5))
// adv: reverse scan gae = (g*l)*gae + delta ; ret: reverse scan acc = g*acc + r.
// Constant-coefficient reverse scans => per-block exact-to-fp32 with geometric halo.
// Structure: per-wave shfl suffix-scans (no barriers) + one 2-barrier cross-wave exchange.

#define T_TOTAL  8388608
#define L_CHUNK  8192
#define NBLK     (T_TOTAL / L_CHUNK)   // 1024
#define NT       512                    // 8 waves
#define M        16                     // elems/thread, NT*M == L_CHUNK
#define W_HALO   1024                   // 2 elems/thread; g^1024 ~ 3.4e-5 -> err ~1e4 << 4.4e6 thr

#define EPSF 0.2f
#define GF   0.99f
#define C1F  0.5f
#define C2F  0.01f
#define AGL  ((float)(0.99 * 0.95))

constexpr float fpowc(double a, int n) {
    double r = 1.0;
    for (int i = 0; i < n; ++i) r *= a;
    return (float)r;
}
// gamma*lambda powers
constexpr float AG2    = fpowc(0.99 * 0.95, 2);
constexpr float AG16   = fpowc(0.99 * 0.95, 16);
constexpr float AG32   = fpowc(0.99 * 0.95, 32);
constexpr float AG64   = fpowc(0.99 * 0.95, 64);
constexpr float AG128  = fpowc(0.99 * 0.95, 128);
constexpr float AG256  = fpowc(0.99 * 0.95, 256);
constexpr float AG512  = fpowc(0.99 * 0.95, 512);
constexpr float AG1024 = fpowc(0.99 * 0.95, 1024);
// gamma powers
constexpr float G2    = fpowc(0.99, 2);
constexpr float G16   = fpowc(0.99, 16);
constexpr float G32   = fpowc(0.99, 32);
constexpr float G64   = fpowc(0.99, 64);
constexpr float G128  = fpowc(0.99, 128);
constexpr float G256  = fpowc(0.99, 256);
constexpr float G512  = fpowc(0.99, 512);
constexpr float G1024 = fpowc(0.99, 1024);

// Inclusive suffix scan across a 64-lane wave with geometric element weight:
// returns S(l) = sum_{l'>=l} w0^(l'-l) * val(l').  Zero barriers.
__device__ __forceinline__ float wave_suffix_scan(float val, float w, int lane) {
#pragma unroll
    for (int s = 1; s < 64; s <<= 1) {
        float o = __shfl_down(val, s, 64);
        o = (lane + s < 64) ? o : 0.0f;
        val += w * o;
        w *= w;
    }
    return val;
}

__global__ __launch_bounds__(NT) void ppo_loss_kernel(
    const float* __restrict__ probs,
    const float* __restrict__ probs_old,
    const float* __restrict__ rewards,
    const float* __restrict__ values,
    float* __restrict__ out)
{
    __shared__ float s_hg[8], s_hr[8], s_wg[8], s_wr[8], s_red[8];

    const int  j    = threadIdx.x;
    const int  lane = j & 63;
    const int  wid  = j >> 6;
    const int  c    = blockIdx.x;
    const long base = (long)c * L_CHUNK;
    const long g0   = base + (long)j * M;

    // ---------------- issue ALL global loads up front ----------------
    // halo first (needed first), then r/v, then p/q (needed last)
    float2 hr2 = make_float2(0.f, 0.f), hv2 = make_float2(0.f, 0.f);
    float  hva = 0.0f;
    const bool has_halo = (c != NBLK - 1);
    if (has_halo) {
        const long hb = base + L_CHUNK + 2L * j;            // 8B aligned
        hr2 = *reinterpret_cast<const float2*>(rewards + hb);
        hv2 = *reinterpret_cast<const float2*>(values  + hb);
        hva = values[hb + 2];
    }
    float4 r4[4], v4[4], p4[4], q4[4];
#pragma unroll
    for (int b = 0; b < 4; ++b) {
        r4[b] = *reinterpret_cast<const float4*>(rewards   + g0 + 4 * b);
        v4[b] = *reinterpret_cast<const float4*>(values    + g0 + 4 * b);
    }
    const float v_next = (g0 + M < T_TOTAL) ? values[g0 + M] : 0.0f;
#pragma unroll
    for (int b = 0; b < 4; ++b) {
        p4[b] = *reinterpret_cast<const float4*>(probs     + g0 + 4 * b);
        q4[b] = *reinterpret_cast<const float4*>(probs_old + g0 + 4 * b);
    }

    float r[M], v[M];
#pragma unroll
    for (int b = 0; b < 4; ++b) {
        r[4*b+0] = r4[b].x; r[4*b+1] = r4[b].y; r[4*b+2] = r4[b].z; r[4*b+3] = r4[b].w;
        v[4*b+0] = v4[b].x; v[4*b+1] = v4[b].y; v[4*b+2] = v4[b].z; v[4*b+3] = v4[b].w;
    }

    // ---------------- halo partial: lane covers halo elems [2*j, 2*j+2) ----------------
    float hg = 0.f, hr = 0.f;
    if (has_halo) {
        const float d0 = hr2.x - hv2.x + GF * hv2.y;
        const float d1 = hr2.y - hv2.y + GF * hva;
        hg = d0 + AGL * d1;
        hr = hr2.x + GF * hr2.y;
    }
    hg = wave_suffix_scan(hg, AG2, lane);   // lane0: sum over this wave's 128 halo elems
    hr = wave_suffix_scan(hr, G2,  lane);
    if (lane == 0) { s_hg[wid] = hg; s_hr[wid] = hr; }

    // ---------------- per-thread Horner partial over own M elems ----------------
    float Pg = 0.f, Pr = 0.f;
#pragma unroll
    for (int i = M - 1; i >= 0; --i) {
        const float vn = (i == M - 1) ? v_next : v[i + 1];
        const float di = r[i] - v[i] + GF * vn;
        Pg = AGL * Pg + di;
        Pr = GF  * Pr + r[i];
    }
    // within-wave inclusive suffix scan (weight AG16 per lane step)
    const float Sg = wave_suffix_scan(Pg, AG16, lane);
    const float Sr = wave_suffix_scan(Pr, G16,  lane);
    if (lane == 0) { s_wg[wid] = Sg; s_wr[wid] = Sr; }
    float sng = __shfl_down(Sg, 1, 64); sng = (lane < 63) ? sng : 0.0f;
    float snr = __shfl_down(Sr, 1, 64); snr = (lane < 63) ? snr : 0.0f;

    // ---------------- heavy VALU while p/q loads land: ratio + entropy ----------------
    float ratio[M];
    float accE = 0.f;
#pragma unroll
    for (int b = 0; b < 4; ++b) {
        const float pa[4] = { p4[b].x, p4[b].y, p4[b].z, p4[b].w };
        const float qa[4] = { q4[b].x, q4[b].y, q4[b].z, q4[b].w };
#pragma unroll
        for (int k = 0; k < 4; ++k) {
            ratio[4*b+k] = __fdividef(pa[k], qa[k]);
            accE -= C2F * pa[k] * __logf(pa[k] + 1e-5f);
        }
    }

    __syncthreads();   // barrier #1

    // halo carry entering position base+L_CHUNK:
    float Kg = 0.f, Kr = 0.f;
#pragma unroll
    for (int w = 7; w >= 0; --w) { Kg = s_hg[w] + AG128 * Kg; Kr = s_hr[w] + G128 * Kr; }
    // carry entering my wave's region from the right
    float Cg = Kg, Cr = Kr;
    for (int w = 7; w > wid; --w) { Cg = s_wg[w] + AG1024 * Cg; Cr = s_wr[w] + G1024 * Cr; }

    // per-lane weight AG16^(63-lane) applied to the wave carry
    const int k63 = 63 - lane;
    float pwg = 1.f, pwr = 1.f;
    if (k63 & 1)  { pwg *= AG16;  pwr *= G16;  }
    if (k63 & 2)  { pwg *= AG32;  pwr *= G32;  }
    if (k63 & 4)  { pwg *= AG64;  pwr *= G64;  }
    if (k63 & 8)  { pwg *= AG128; pwr *= G128; }
    if (k63 & 16) { pwg *= AG256; pwr *= G256; }
    if (k63 & 32) { pwg *= AG512; pwr *= G512; }

    float y  = sng + pwg * Cg;   // advantage-scan value entering my run
    float tt = snr + pwr * Cr;   // return-scan value entering my run

    // ---------------- fused reverse scan + loss over own M elems ----------------
    float acc = accE;
#pragma unroll
    for (int i = M - 1; i >= 0; --i) {
        const float vn = (i == M - 1) ? v_next : v[i + 1];
        const float di = r[i] - v[i] + GF * vn;
        y  = AGL * y  + di;
        tt = GF  * tt + r[i];
        const float rt   = ratio[i];
        const float cl   = fminf(fmaxf(rt, 1.0f - EPSF), 1.0f + EPSF);
        const float term = fminf(rt * y, cl * y);
        const float vd   = v[i] - tt;
        acc = fmaf(C1F * vd, vd, acc) - term;
    }

    // ---------------- reduce: wave shfl, then 8 partials ----------------
#pragma unroll
    for (int s = 32; s >= 1; s >>= 1) acc += __shfl_down(acc, s, 64);
    if (lane == 0) s_red[wid] = acc;
    __syncthreads();   // barrier #2
    if (j == 0) {
        float t = 0.f;
#pragma unroll
        for (int w = 0; w < 8; ++w) t += s_red[w];
        atomicAdd(out, t);
    }
}

extern "C" void kernel_launch(void* const* d_in, const int* in_sizes, int n_in,
                              void* d_out, int out_size, void* d_ws, size_t ws_size,
                              hipStream_t stream) {
    const float* probs     = (const float*)d_in[0];
    const float* probs_old = (const float*)d_in[1];
    const float* rewards   = (const float*)d_in[2];
    const float* values    = (const float*)d_in[3];
    float* out = (float*)d_out;

    hipMemsetAsync(out, 0, sizeof(float), stream);   // d_out is poisoned 0xAA before every call
    ppo_loss_kernel<<<NBLK, NT, 0, stream>>>(probs, probs_old, rewards, values, out);
}

// Round 3
// 150.294 us; speedup vs baseline: 1.0710x; 1.0247x over previous
//
#include <hip/hip_runtime.h>

// PPO loss, T = 2^23 fp32.
// out = -sum(min(ratio*adv, clip(ratio)*adv)) + C1*sum((v-ret)^2) - C2*sum(p*log(p+1e-5))
// adv: reverse scan gae = (gl)*gae + delta ; ret: reverse scan acc = g*acc + r.
// Constant-coefficient reverse scans => per-block exact-to-fp32 with geometric halo (W=1024,
// absmax was 0.0 at this window in rounds 1-2).
//
// This round: dense-coalesced lane-interleaved layout (every load instr = 1KB contiguous),
// scan restructured accordingly (per-row wave scans, weight a^4 per lane step), and the
// single-address atomic replaced by d_ws partials + a tiny second reduction kernel.

#define T_TOTAL  8388608
#define L_CHUNK  4096
#define NBLK     (T_TOTAL / L_CHUNK)   // 2048
#define NT       256                   // 4 waves
#define NW       4
#define ROWS     4                     // rows/wave; row = 256 consecutive elems (64 lanes x 4)

#define EPSF 0.2f
#define GF   0.99f
#define C1F  0.5f
#define C2F  0.01f
#define AGLF ((float)(0.99 * 0.95))

constexpr float fpowc(double a, int n) {
    double r = 1.0;
    for (int i = 0; i < n; ++i) r *= a;
    return (float)r;
}
// (gamma*lambda)^n
constexpr float AG4    = fpowc(0.99 * 0.95, 4);
constexpr float AG8    = fpowc(0.99 * 0.95, 8);
constexpr float AG16   = fpowc(0.99 * 0.95, 16);
constexpr float AG32   = fpowc(0.99 * 0.95, 32);
constexpr float AG64   = fpowc(0.99 * 0.95, 64);
constexpr float AG128  = fpowc(0.99 * 0.95, 128);
constexpr float AG256  = fpowc(0.99 * 0.95, 256);
constexpr float AG512  = fpowc(0.99 * 0.95, 512);
constexpr float AG768  = fpowc(0.99 * 0.95, 768);
constexpr float AG1024 = fpowc(0.99 * 0.95, 1024);
// gamma^n
constexpr float G4    = fpowc(0.99, 4);
constexpr float G8    = fpowc(0.99, 8);
constexpr float G16   = fpowc(0.99, 16);
constexpr float G32   = fpowc(0.99, 32);
constexpr float G64   = fpowc(0.99, 64);
constexpr float G128  = fpowc(0.99, 128);
constexpr float G256  = fpowc(0.99, 256);
constexpr float G512  = fpowc(0.99, 512);
constexpr float G768  = fpowc(0.99, 768);
constexpr float G1024 = fpowc(0.99, 1024);

// Inclusive wave suffix scan with geometric lane-step weight w0 (zero barriers):
// returns U(l) = sum_{l'>=l} w0^(l'-l) * val(l')
__device__ __forceinline__ float wscan(float val, float w, int lane) {
#pragma unroll
    for (int s = 1; s < 64; s <<= 1) {
        float o = __shfl_down(val, s, 64);
        val += (lane + s < 64) ? w * o : 0.0f;
        w *= w;
    }
    return val;
}

__global__ __launch_bounds__(NT) void ppo_main(
    const float* __restrict__ probs,
    const float* __restrict__ probs_old,
    const float* __restrict__ rewards,
    const float* __restrict__ values,
    float* __restrict__ part)
{
    __shared__ float sGg[NW], sGr[NW], sHg[NW], sHr[NW], sRed[NW];

    const int  j    = threadIdx.x;
    const int  lane = j & 63;
    const int  wid  = j >> 6;
    const int  c    = blockIdx.x;
    const long base = (long)c * L_CHUNK;
    const long wb   = base + (long)wid * (ROWS * 256);   // wave covers 1024 elems
    const int  l4   = lane * 4;

    const bool has_halo = (c != NBLK - 1);

    // ---------------- issue all global loads up front (all dense 1KB/instr) ----------------
    float4 hr4 = make_float4(0,0,0,0), hv4 = make_float4(0,0,0,0);
    float  hvl = 0.0f;
    if (has_halo) {
        const long hb = base + L_CHUNK + (long)wid * 256 + l4;   // wave's halo row
        hr4 = *reinterpret_cast<const float4*>(rewards + hb);
        hv4 = *reinterpret_cast<const float4*>(values  + hb);
        hvl = values[base + L_CHUNK + (long)wid * 256 + 256];    // uniform addr, in range
    }
    float4 r4[ROWS], v4[ROWS], p4[ROWS], q4[ROWS];
#pragma unroll
    for (int b = 0; b < ROWS; ++b) {
        const long a = wb + b * 256 + l4;
        r4[b] = *reinterpret_cast<const float4*>(rewards + a);
        v4[b] = *reinterpret_cast<const float4*>(values  + a);
    }
    float vlast = 0.0f;
    { const long a = wb + 1024; if (a < T_TOTAL) vlast = values[a]; }  // v_T = 0
#pragma unroll
    for (int b = 0; b < ROWS; ++b) {
        const long a = wb + b * 256 + l4;
        p4[b] = *reinterpret_cast<const float4*>(probs     + a);
        q4[b] = *reinterpret_cast<const float4*>(probs_old + a);
    }

    // ---------------- halo row: total weighted sum over 256 elems ----------------
    float Uhg = 0.0f, Uhr = 0.0f;
    if (has_halo) {
        float t = __shfl_down(hv4.x, 1, 64);
        const float vn3 = (lane < 63) ? t : hvl;
        const float d0 = hr4.x - hv4.x + GF * hv4.y;
        const float d1 = hr4.y - hv4.y + GF * hv4.z;
        const float d2 = hr4.z - hv4.z + GF * hv4.w;
        const float d3 = hr4.w - hv4.w + GF * vn3;
        const float Pg = d0 + AGLF * (d1 + AGLF * (d2 + AGLF * d3));
        const float Pr = hr4.x + GF * (hr4.y + GF * (hr4.z + GF * hr4.w));
        Uhg = wscan(Pg, AG4, lane);
        Uhr = wscan(Pr, G4, lane);
    }
    if (lane == 0) { sHg[wid] = Uhg; sHr[wid] = Uhr; }

    // ---------------- per-row wave scans ----------------
    // row b elems: wb + 256b + 4l + k. U_b(l) = sum_{l'>=l} (a^4)^(l'-l) * P_b(l').
    float Ug[ROWS], Ur[ROWS];
#pragma unroll
    for (int b = 0; b < ROWS; ++b) {
        const float nv0 = (b < ROWS - 1) ? __shfl(v4[b + 1].x, 0, 64) : vlast;
        float t = __shfl_down(v4[b].x, 1, 64);
        const float vn3 = (lane < 63) ? t : nv0;
        const float d0 = r4[b].x - v4[b].x + GF * v4[b].y;
        const float d1 = r4[b].y - v4[b].y + GF * v4[b].z;
        const float d2 = r4[b].z - v4[b].z + GF * v4[b].w;
        const float d3 = r4[b].w - v4[b].w + GF * vn3;
        const float Pg = d0 + AGLF * (d1 + AGLF * (d2 + AGLF * d3));
        const float Pr = r4[b].x + GF * (r4[b].y + GF * (r4[b].z + GF * r4[b].w));
        Ug[b] = wscan(Pg, AG4, lane);
        Ur[b] = wscan(Pr, G4, lane);
    }

    // local row chain with zero entering carry: Wl_b = U_b(0) + a^256 * Wl_{b+1}
    float Wlg[ROWS + 1], Wlr[ROWS + 1];
    Wlg[ROWS] = 0.0f; Wlr[ROWS] = 0.0f;
#pragma unroll
    for (int b = ROWS - 1; b >= 0; --b) {
        Wlg[b] = __shfl(Ug[b], 0, 64) + AG256 * Wlg[b + 1];
        Wlr[b] = __shfl(Ur[b], 0, 64) + G256  * Wlr[b + 1];
    }
    if (lane == 0) { sGg[wid] = Wlg[0]; sGr[wid] = Wlr[0]; }   // wave totals (1024 elems)

    __syncthreads();   // barrier #1

    // halo carry at block end, then carry entering this wave's region from the right
    const float Kg = sHg[0] + AG256 * (sHg[1] + AG256 * (sHg[2] + AG256 * sHg[3]));
    const float Kr = sHr[0] + G256  * (sHr[1] + G256  * (sHr[2] + G256  * sHr[3]));
    float Cg = Kg, Cr = Kr;
    for (int w = 3; w > wid; --w) {   // wave-uniform trip count
        Cg = sGg[w] + AG1024 * Cg;
        Cr = sGr[w] + G1024  * Cr;
    }

    // per-lane carry weight (a^4)^(63-lane)
    const int k63 = 63 - lane;
    float wg = 1.0f, wr = 1.0f;
    if (k63 & 1)  { wg *= AG4;   wr *= G4;   }
    if (k63 & 2)  { wg *= AG8;   wr *= G8;   }
    if (k63 & 4)  { wg *= AG16;  wr *= G16;  }
    if (k63 & 8)  { wg *= AG32;  wr *= G32;  }
    if (k63 & 16) { wg *= AG64;  wr *= G64;  }
    if (k63 & 32) { wg *= AG128; wr *= G128; }

    // ---------------- final pass: per-row fused reverse scan + loss ----------------
    float acc = 0.0f;
#pragma unroll
    for (int b = 0; b < ROWS; ++b) {
        // W'_{b+1} = Wl_{b+1} + a^(256*(3-b)) * C   (carry injected by linearity)
        const float cwg = (b == 0) ? AG768 : (b == 1) ? AG512 : (b == 2) ? AG256 : 1.0f;
        const float cwr = (b == 0) ? G768  : (b == 1) ? G512  : (b == 2) ? G256  : 1.0f;
        const float Wng = Wlg[b + 1] + cwg * Cg;
        const float Wnr = Wlr[b + 1] + cwr * Cr;
        float ugs = __shfl_down(Ug[b], 1, 64); ugs = (lane < 63) ? ugs : 0.0f;
        float urs = __shfl_down(Ur[b], 1, 64); urs = (lane < 63) ? urs : 0.0f;
        float y  = ugs + wg * Wng;   // scan value entering this lane's 4-run (from elem 4l+4)
        float tt = urs + wr * Wnr;

        const float nv0 = (b < ROWS - 1) ? __shfl(v4[b + 1].x, 0, 64) : vlast;
        float t2 = __shfl_down(v4[b].x, 1, 64);
        const float vn3 = (lane < 63) ? t2 : nv0;

        const float rr[4]  = { r4[b].x, r4[b].y, r4[b].z, r4[b].w };
        const float vv[4]  = { v4[b].x, v4[b].y, v4[b].z, v4[b].w };
        const float vnx[4] = { v4[b].y, v4[b].z, v4[b].w, vn3 };
        const float pp[4]  = { p4[b].x, p4[b].y, p4[b].z, p4[b].w };
        const float qq[4]  = { q4[b].x, q4[b].y, q4[b].z, q4[b].w };
#pragma unroll
        for (int k = 3; k >= 0; --k) {
            const float d = rr[k] - vv[k] + GF * vnx[k];
            y  = fmaf(AGLF, y, d);      // advantage at elem
            tt = fmaf(GF, tt, rr[k]);   // value target at elem
            const float rt   = __fdividef(pp[k], qq[k]);
            const float cl   = fminf(fmaxf(rt, 1.0f - EPSF), 1.0f + EPSF);
            const float term = fminf(rt * y, cl * y);
            const float vd   = vv[k] - tt;
            acc = fmaf(C1F * vd, vd, acc) - term - C2F * pp[k] * __logf(pp[k] + 1e-5f);
        }
    }

    // ---------------- block reduce -> d_ws partial ----------------
#pragma unroll
    for (int s = 32; s >= 1; s >>= 1) acc += __shfl_down(acc, s, 64);
    if (lane == 0) sRed[wid] = acc;
    __syncthreads();   // barrier #2
    if (j == 0) part[c] = (sRed[0] + sRed[1]) + (sRed[2] + sRed[3]);
}

__global__ __launch_bounds__(256) void ppo_reduce(
    const float* __restrict__ part, float* __restrict__ out)
{
    __shared__ float s[4];
    const int j = threadIdx.x, lane = j & 63, wid = j >> 6;
    const float4 a = *reinterpret_cast<const float4*>(part + j * 8);
    const float4 b = *reinterpret_cast<const float4*>(part + j * 8 + 4);
    float x = ((a.x + a.y) + (a.z + a.w)) + ((b.x + b.y) + (b.z + b.w));
#pragma unroll
    for (int s2 = 32; s2 >= 1; s2 >>= 1) x += __shfl_down(x, s2, 64);
    if (lane == 0) s[wid] = x;
    __syncthreads();
    if (j == 0) out[0] = (s[0] + s[1]) + (s[2] + s[3]);
}

extern "C" void kernel_launch(void* const* d_in, const int* in_sizes, int n_in,
                              void* d_out, int out_size, void* d_ws, size_t ws_size,
                              hipStream_t stream) {
    const float* probs     = (const float*)d_in[0];
    const float* probs_old = (const float*)d_in[1];
    const float* rewards   = (const float*)d_in[2];
    const float* values    = (const float*)d_in[3];
    float* part = (float*)d_ws;            // NBLK floats of scratch
    float* out  = (float*)d_out;

    ppo_main<<<NBLK, NT, 0, stream>>>(probs, probs_old, rewards, values, part);
    ppo_reduce<<<1, 256, 0, stream>>>(part, out);
}